// Round 17
// baseline (192.719 us; speedup 1.0000x reference)
//
#include <hip/hip_runtime.h>
#include <math.h>

#define S_LEN 256
#define BATCH 512
#define ROWS (S_LEN * BATCH)
#define VOCAB 128000

typedef float v2f __attribute__((ext_vector_type(2)));

// ---------------------------------------------------------------------------
// Compile-time reproduction of np.random.RandomState(seed) op streams.
// ---------------------------------------------------------------------------
struct MTState {
    unsigned mt[624];
    int idx;
    constexpr MTState(unsigned seed) : mt{}, idx(624) {
        mt[0] = seed;
        for (int i = 1; i < 624; ++i)
            mt[i] = 1812433253u * (mt[i - 1] ^ (mt[i - 1] >> 30)) + (unsigned)i;
    }
    constexpr unsigned next() {
        if (idx >= 624) {
            for (int i = 0; i < 624; ++i) {
                unsigned y = (mt[i] & 0x80000000u) | (mt[(i + 1) % 624] & 0x7fffffffu);
                mt[i] = mt[(i + 397) % 624] ^ (y >> 1) ^ ((y & 1u) ? 2567483615u : 0u);
            }
            idx = 0;
        }
        unsigned y = mt[idx++];
        y ^= y >> 11;
        y ^= (y << 7)  & 2636928640u;
        y ^= (y << 15) & 4022730752u;
        y ^= y >> 18;
        return y;
    }
};

struct OpsTab {
    int   k [4][20];
    int   w0[4][20];
    int   w1[4][20];
    float t [4][20];
};

constexpr OpsTab make_ops() {
    OpsTab o{};
    for (int seed = 0; seed < 4; ++seed) {
        MTState rng((unsigned)seed);
        for (int i = 0; i < 20; ++i) {
            unsigned k = rng.next() & 3u;            // randint(4)
            if (k < 3u) {
                int w = (int)(rng.next() & 3u);      // randint(4)
                unsigned A = rng.next(), B = rng.next();  // rk_double
                double d = ((double)(A >> 5) * 67108864.0 + (double)(B >> 6))
                           / 9007199254740992.0;
                o.k[seed][i]  = (int)k;
                o.w0[seed][i] = w;
                o.w1[seed][i] = 0;
                o.t[seed][i]  = (float)(6.283185307179586 * d);
            } else {
                int w0 = (int)(rng.next() & 3u);     // randint(4)
                unsigned v = rng.next() & 3u;        // randint(3): reject >2
                while (v > 2u) v = rng.next() & 3u;
                o.k[seed][i]  = 3;
                o.w0[seed][i] = w0;
                o.w1[seed][i] = (int)((w0 + 1 + (int)v) & 3);
                o.t[seed][i]  = 0.f;
            }
        }
    }
    return o;
}

__constant__ OpsTab OPS = make_ops();

// factor for product-to-sum expansion: enc_j*enc_k per wire.
__device__ inline float pfac(int t, int bj, int bk) {
    if (bj == bk)
        return (t == 0) ? 0.5f : (t == 1) ? (bj ? -0.5f : 0.5f) : 0.f;
    return (t == 2) ? 0.5f : 0.f;
}

// ---------------------------------------------------------------------------
// Setup: lane-parallel circuit fold -> M (LDS) -> Q = Re(M^T D_w M) -> T
// tensor (16 (g,w) pairs x 81 coeffs over {1,cos,sin}^4) -> global.
// ---------------------------------------------------------------------------
__global__ __launch_bounds__(1024) void setup_kernel(const float* __restrict__ qrx,
                                                     const float* __restrict__ qry,
                                                     const float* __restrict__ qrz,
                                                     const float* __restrict__ qcrx,
                                                     float* __restrict__ Tg) {
    __shared__ float Mr[4 * 256];
    __shared__ float Mi[4 * 256];
    __shared__ float Q[16 * 256];

    int tid = threadIdx.x;
    int wv  = tid >> 6;
    int l   = tid & 63;
    int g   = wv >> 2;
    int r   = l & 15;
    int col = (wv & 3) * 4 + (l >> 4);

    float ar = (r == col) ? 1.f : 0.f;
    float ai = 0.f;
    int lbase = l & 48;

    for (int o = 0; o < 20; ++o) {
        int   k  = OPS.k[g][o];
        int   w  = OPS.w0[g][o];
        float th = OPS.t[g][o];
        if (k == 3) {
            int M1  = 8 >> OPS.w1[g][o];
            int M0  = 8 >> w;
            int src = lbase | (r ^ M1);
            float br = __shfl(ar, src, 64);
            float bi = __shfl(ai, src, 64);
            bool ctrl = (r & M0) != 0;
            ar = ctrl ? br : ar;
            ai = ctrl ? bi : ai;
        } else {
            int M = 8 >> w;
            float c = cosf(0.5f * th), s = sinf(0.5f * th);
            bool hi = (r & M) != 0;
            float Ar = c, Ai = 0.f, Br = 0.f, Bi = 0.f;
            if (k == 0) { Bi = -s; }                       // RX
            else if (k == 1) { Br = hi ? s : -s; }         // RY
            else { Ai = hi ? s : -s; }                     // RZ
            int src = lbase | (r ^ M);
            float br = __shfl(ar, src, 64);
            float bi = __shfl(ai, src, 64);
            float nr = Ar * ar - Ai * ai + Br * br - Bi * bi;
            float ni = Ar * ai + Ai * ar + Br * bi + Bi * br;
            ar = nr; ai = ni;
        }
    }

    for (int w = 0; w < 4; ++w) {
        int M  = 8 >> w;
        int M1 = 8 >> ((w + 1) & 3);
        bool hi = (r & M) != 0;
        int src = lbase | (r ^ M);
        float th, c, s, br, bi, nr, ni;

        th = qrx[g * 4 + w]; c = cosf(0.5f * th); s = sinf(0.5f * th);
        br = __shfl(ar, src, 64); bi = __shfl(ai, src, 64);
        nr = c * ar + s * bi;  ni = c * ai - s * br;       // RX
        ar = nr; ai = ni;

        th = qry[g * 4 + w]; c = cosf(0.5f * th); s = sinf(0.5f * th);
        br = __shfl(ar, src, 64); bi = __shfl(ai, src, 64);
        { float B = hi ? s : -s;
          nr = c * ar + B * br;  ni = c * ai + B * bi; }   // RY
        ar = nr; ai = ni;

        th = qrz[g * 4 + w]; c = cosf(0.5f * th); s = sinf(0.5f * th);
        { float Ai2 = hi ? s : -s;
          nr = c * ar - Ai2 * ai;  ni = c * ai + Ai2 * ar; } // RZ
        ar = nr; ai = ni;

        th = qcrx[g * 4 + w]; c = cosf(0.5f * th); s = sinf(0.5f * th);
        int src1 = lbase | (r ^ M1);
        br = __shfl(ar, src1, 64); bi = __shfl(ai, src1, 64);
        bool ctrl = hi;
        nr = c * ar + s * bi;  ni = c * ai - s * br;       // CRX
        ar = ctrl ? nr : ar;
        ai = ctrl ? ni : ai;
    }

    Mr[g * 256 + r * 16 + col] = ar;
    Mi[g * 256 + r * 16 + col] = ai;
    __syncthreads();

    for (int n = 0; n < 4; ++n) {
        int i  = tid * 4 + n;
        int gw = i >> 8, j = (i >> 4) & 15, kk = i & 15;
        int gg2 = gw >> 2, w = gw & 3;
        float acc = 0.f;
        for (int rr = 0; rr < 16; ++rr) {
            float sgn = ((rr >> (3 - w)) & 1) ? -1.f : 1.f;
            float mrj = Mr[gg2 * 256 + rr * 16 + j], mrk = Mr[gg2 * 256 + rr * 16 + kk];
            float mij = Mi[gg2 * 256 + rr * 16 + j], mik = Mi[gg2 * 256 + rr * 16 + kk];
            acc += sgn * (mrj * mrk + mij * mik);
        }
        Q[gw * 256 + j * 16 + kk] = acc;
    }
    __syncthreads();

    if (tid < 144) {
        int gw = tid / 9, rem = tid % 9, t0 = rem / 3, t1 = rem % 3;
        float acc[3][3] = {};
        for (int jk = 0; jk < 256; ++jk) {
            int j = jk >> 4, kq = jk & 15;
            int bj0 = (j >> 3) & 1, bk0 = (kq >> 3) & 1;
            int bj1 = (j >> 2) & 1, bk1 = (kq >> 2) & 1;
            int bj2 = (j >> 1) & 1, bk2 = (kq >> 1) & 1;
            int bj3 = j & 1,        bk3 = kq & 1;
            float f01 = pfac(t0, bj0, bk0) * pfac(t1, bj1, bk1);
            float base = Q[gw * 256 + jk] * f01;
#pragma unroll
            for (int t2 = 0; t2 < 3; ++t2) {
                float f2 = pfac(t2, bj2, bk2);
#pragma unroll
                for (int t3 = 0; t3 < 3; ++t3) {
                    float f3 = pfac(t3, bj3, bk3);
                    acc[t2][t3] = fmaf(base, f2 * f3, acc[t2][t3]);
                }
            }
        }
#pragma unroll
        for (int t2 = 0; t2 < 3; ++t2)
#pragma unroll
            for (int t3 = 0; t3 < 3; ++t3)
                Tg[gw * 81 + t0 * 27 + t1 * 9 + t2 * 3 + t3] = acc[t2][t3];
    }
}

// ---------------------------------------------------------------------------
// proj kernel v5 (R15 measured-ok): dense global loads + DPP row_shr
// reduction, zero LDS.  Lane ch==15 of each 16-group stores a float4.
// ---------------------------------------------------------------------------
template <int CTRL>
__device__ inline float dpp_shr_add(float p) {
    int t = __builtin_amdgcn_update_dpp(0, __float_as_int(p), CTRL, 0xf, 0xf, true);
    return p + __int_as_float(t);
}

__global__ __launch_bounds__(256) void proj_kernel(const float* __restrict__ emb,
                                                   const float* __restrict__ lin_w,
                                                   const float* __restrict__ lin_b,
                                                   float* __restrict__ proj) {
    int tid = threadIdx.x;
    int l   = tid & 63;
    int wv  = tid >> 6;          // q-group
    int ch  = l & 15;            // d-chunk lane
    int rl  = l >> 4;            // row within group of 4

    float wq[4][16];
#pragma unroll
    for (int qq = 0; qq < 4; ++qq) {
        const float* wr = lin_w + (wv * 4 + qq) * 260 + ch * 4;
#pragma unroll
        for (int j = 0; j < 4; ++j) {
            float4 t = *(const float4*)(wr + j * 64);
            wq[qq][j * 4 + 0] = t.x; wq[qq][j * 4 + 1] = t.y;
            wq[qq][j * 4 + 2] = t.z; wq[qq][j * 4 + 3] = t.w;
        }
    }
    float4 bz = *(const float4*)(lin_b + wv * 4);

    const int ntiles = VOCAB / 16;   // 8000
    for (int tile = blockIdx.x; tile < ntiles; tile += gridDim.x) {
        const float* base = emb + (size_t)tile * 16 * 256;
#pragma unroll
        for (int r4 = 0; r4 < 4; ++r4) {
            int row = r4 * 4 + rl;
            const float* rp = base + row * 256 + ch * 4;
            float xs[16];
            *(float4*)&xs[0]  = *(const float4*)(rp + 0 * 64);
            *(float4*)&xs[4]  = *(const float4*)(rp + 1 * 64);
            *(float4*)&xs[8]  = *(const float4*)(rp + 2 * 64);
            *(float4*)&xs[12] = *(const float4*)(rp + 3 * 64);

            float p0 = 0.f, p1 = 0.f, p2 = 0.f, p3 = 0.f;
#pragma unroll
            for (int d = 0; d < 16; ++d) {
                p0 = fmaf(xs[d], wq[0][d], p0);
                p1 = fmaf(xs[d], wq[1][d], p1);
                p2 = fmaf(xs[d], wq[2][d], p2);
                p3 = fmaf(xs[d], wq[3][d], p3);
            }

            p0 = dpp_shr_add<0x111>(p0); p1 = dpp_shr_add<0x111>(p1);
            p2 = dpp_shr_add<0x111>(p2); p3 = dpp_shr_add<0x111>(p3);
            p0 = dpp_shr_add<0x112>(p0); p1 = dpp_shr_add<0x112>(p1);
            p2 = dpp_shr_add<0x112>(p2); p3 = dpp_shr_add<0x112>(p3);
            p0 = dpp_shr_add<0x114>(p0); p1 = dpp_shr_add<0x114>(p1);
            p2 = dpp_shr_add<0x114>(p2); p3 = dpp_shr_add<0x114>(p3);
            p0 = dpp_shr_add<0x118>(p0); p1 = dpp_shr_add<0x118>(p1);
            p2 = dpp_shr_add<0x118>(p2); p3 = dpp_shr_add<0x118>(p3);

            if (ch == 15) {
                float4 o = make_float4(p0 + bz.x, p1 + bz.y, p2 + bz.z, p3 + bz.w);
                *(float4*)(proj + ((size_t)(tile * 16 + row) * 16 + wv * 4)) = o;
            }
        }
    }
}

// ---------------------------------------------------------------------------
// Recurrence — instruction diet (R15 was ~170 VALU/step, issue-limited):
// 1. Polynomial re-ordered t2->t1->t0->t3 and T stored as 27 v2f + 27 scalar
//    so each stage is v_pk_fma_f32 on the vector half: 80 FMA -> 54 instr.
// 2. __sincosf -> a*(1/2pi) + raw v_sin/v_cos (angles are O(10), in range):
//    ~40 -> 12 instr.
// Everything else R9-exact (best measured 89.4 us).
// ---------------------------------------------------------------------------
__device__ inline float fast_sig(float k, float x) {
    return __builtin_amdgcn_rcpf(1.f + __expf(-k * x));
}

#define INV2PI 0.15915494309189535f

__global__ __launch_bounds__(64)
__attribute__((amdgpu_waves_per_eu(1, 1)))
void lstm_kernel(const float* __restrict__ lin_w,
                 const float* __restrict__ Tg,
                 const int* __restrict__ sent,
                 const float* __restrict__ proj,
                 float* __restrict__ outs) {
    int l = threadIdx.x;
    int g = l & 3;
    int w = (l >> 2) & 3;
    int q = l >> 4;
    int b = blockIdx.x * 4 + q;

    // T split: TV[c3] = {T[..t3=0], T[..t3=1]} (v2f), TS[c3] = T[..t3=2],
    // where c3 = t0*9 + t1*3 + t2.
    v2f   TV[27];
    float TS[27];
#pragma unroll
    for (int c = 0; c < 27; ++c) {
        const float* tp = Tg + (g * 4 + w) * 81 + c * 3;
        TV[c] = (v2f){tp[0], tp[1]};
        TS[c] = tp[2];
    }

    float whp[4][4];
#pragma unroll
    for (int qq = 0; qq < 4; ++qq)
#pragma unroll
        for (int k = 0; k < 4; ++k)
            whp[qq][k] = lin_w[(g * 4 + qq) * 260 + 256 + ((w - k) & 3)];

    const float kk = (g == 2) ? 2.f : 1.f;
    const float sc = (g == 2) ? 2.f : 1.f;
    const float of = (g == 2) ? 1.f : 0.f;

    float hr0 = 0.f, hr1 = 0.f, hr2 = 0.f, hr3 = 0.f, cst = 0.f;

    const int* sp = sent + b;
    float* op = outs + (size_t)b * 4 + w;

    auto tokat = [&](int sidx) { return sp[(size_t)(sidx & 255) * BATCH]; };
    auto rowat = [&](int tok)  { return *(const float4*)(proj + (size_t)tok * 16 + g * 4); };

    int tk0 = tokat(4), tk1 = tokat(5), tk2 = tokat(6), tk3 = tokat(7);
    float4 A0 = rowat(tokat(0));
    float4 A1 = rowat(tokat(1));
    float4 A2 = rowat(tokat(2));
    float4 A3 = rowat(tokat(3));

    auto step = [&](float4 ax, int sidx) {
        float a0 = fmaf(whp[0][3], hr3, fmaf(whp[0][2], hr2, fmaf(whp[0][1], hr1, fmaf(whp[0][0], hr0, ax.x))));
        float a1 = fmaf(whp[1][3], hr3, fmaf(whp[1][2], hr2, fmaf(whp[1][1], hr1, fmaf(whp[1][0], hr0, ax.y))));
        float a2 = fmaf(whp[2][3], hr3, fmaf(whp[2][2], hr2, fmaf(whp[2][1], hr1, fmaf(whp[2][0], hr0, ax.z))));
        float a3 = fmaf(whp[3][3], hr3, fmaf(whp[3][2], hr2, fmaf(whp[3][1], hr1, fmaf(whp[3][0], hr0, ax.w))));

        // raw-hardware sincos (input in revolutions)
        float r0 = a0 * INV2PI, r1 = a1 * INV2PI, r2 = a2 * INV2PI, r3 = a3 * INV2PI;
        float s0 = __builtin_amdgcn_sinf(r0), c0 = __builtin_amdgcn_cosf(r0);
        float s1 = __builtin_amdgcn_sinf(r1), c1 = __builtin_amdgcn_cosf(r1);
        float s2 = __builtin_amdgcn_sinf(r2), c2 = __builtin_amdgcn_cosf(r2);
        float s3 = __builtin_amdgcn_sinf(r3), c3 = __builtin_amdgcn_cosf(r3);

        v2f c2v = {c2, c2}, s2v = {s2, s2};
        v2f c1v = {c1, c1}, s1v = {s1, s1};
        v2f c0v = {c0, c0}, s0v = {s0, s0};

        // Stage A: contract t2 (coeffs c2,s2).  9 cells.
        v2f   yAv[9];
        float yAs[9];
#pragma unroll
        for (int c = 0; c < 9; ++c) {
            yAv[c] = __builtin_elementwise_fma(s2v, TV[c * 3 + 2],
                       __builtin_elementwise_fma(c2v, TV[c * 3 + 1], TV[c * 3 + 0]));
            yAs[c] = fmaf(s2, TS[c * 3 + 2], fmaf(c2, TS[c * 3 + 1], TS[c * 3 + 0]));
        }
        // Stage B: contract t1 (c1,s1).  3 cells.
        v2f   yBv[3];
        float yBs[3];
#pragma unroll
        for (int c = 0; c < 3; ++c) {
            yBv[c] = __builtin_elementwise_fma(s1v, yAv[c * 3 + 2],
                       __builtin_elementwise_fma(c1v, yAv[c * 3 + 1], yAv[c * 3 + 0]));
            yBs[c] = fmaf(s1, yAs[c * 3 + 2], fmaf(c1, yAs[c * 3 + 1], yAs[c * 3 + 0]));
        }
        // Stage C: contract t0 (c0,s0).
        v2f   yCv = __builtin_elementwise_fma(s0v, yBv[2],
                      __builtin_elementwise_fma(c0v, yBv[1], yBv[0]));
        float yCs = fmaf(s0, yBs[2], fmaf(c0, yBs[1], yBs[0]));
        // Stage D: contract t3 (c3,s3).
        float Z = fmaf(s3, yCs, fmaf(c3, yCv.y, yCv.x));

        float act = fmaf(sc, fast_sig(kk, Z), -of);

        int ai2 = __float_as_int(act);
        float f  = __int_as_float(__builtin_amdgcn_update_dpp(0, ai2, 0x00, 0xf, 0xf, true));
        float ii = __int_as_float(__builtin_amdgcn_update_dpp(0, ai2, 0x55, 0xf, 0xf, true));
        float gg = __int_as_float(__builtin_amdgcn_update_dpp(0, ai2, 0xAA, 0xf, 0xf, true));
        float oo = __int_as_float(__builtin_amdgcn_update_dpp(0, ai2, 0xFF, 0xf, 0xf, true));

        cst = fmaf(f, cst, ii * gg);
        float tn = fmaf(2.f, fast_sig(2.f, cst), -1.f);
        float hme = oo * tn;

        if (g == 0) op[(size_t)sidx * 2048] = hme;

        int hi = __float_as_int(hme);
        hr0 = hme;
        hr1 = __int_as_float(__builtin_amdgcn_update_dpp(hi, hi, 0x124, 0xf, 0xf, false));
        hr2 = __int_as_float(__builtin_amdgcn_update_dpp(hi, hi, 0x128, 0xf, 0xf, false));
        hr3 = __int_as_float(__builtin_amdgcn_update_dpp(hi, hi, 0x12C, 0xf, 0xf, false));
    };

    for (int s = 0; s < S_LEN; s += 4) {
        step(A0, s);     A0 = rowat(tk0); tk0 = tokat(s + 8);
        step(A1, s + 1); A1 = rowat(tk1); tk1 = tokat(s + 9);
        step(A2, s + 2); A2 = rowat(tk2); tk2 = tokat(s + 10);
        step(A3, s + 3); A3 = rowat(tk3); tk3 = tokat(s + 11);
    }
}

// ---------------------------------------------------------------------------
// logits + log_softmax (R9 exact): wave per (s,b) row, lane = tag.
// ---------------------------------------------------------------------------
__global__ __launch_bounds__(256) void logits_kernel(const float* __restrict__ outs,
                                                     const float* __restrict__ tag_w,
                                                     const float* __restrict__ tag_b,
                                                     float* __restrict__ out) {
    int l = threadIdx.x & 63;
    int wid = (blockIdx.x * blockDim.x + threadIdx.x) >> 6;
    int nw  = (gridDim.x * blockDim.x) >> 6;

    float4 w = *(const float4*)(tag_w + l * 4);
    float bb = tag_b[l];

    for (int row = wid; row < ROWS; row += nw) {
        float4 h = *(const float4*)(outs + (size_t)row * 4);
        float z = fmaf(h.x, w.x, fmaf(h.y, w.y, fmaf(h.z, w.z, fmaf(h.w, w.w, bb))));
        float m = z;
#pragma unroll
        for (int d = 1; d < 64; d <<= 1) m = fmaxf(m, __shfl_xor(m, d, 64));
        float e = __expf(z - m);
        float ssum = e;
#pragma unroll
        for (int d = 1; d < 64; d <<= 1) ssum += __shfl_xor(ssum, d, 64);
        out[(size_t)row * 64 + l] = (z - m) - __logf(ssum);
    }
}

// ---------------------------------------------------------------------------
extern "C" void kernel_launch(void* const* d_in, const int* in_sizes, int n_in,
                              void* d_out, int out_size, void* d_ws, size_t ws_size,
                              hipStream_t stream) {
    const int*   sent  = (const int*)d_in[0];
    const float* emb   = (const float*)d_in[1];
    const float* lin_w = (const float*)d_in[2];
    const float* lin_b = (const float*)d_in[3];
    const float* qrx   = (const float*)d_in[4];
    const float* qry   = (const float*)d_in[5];
    const float* qrz   = (const float*)d_in[6];
    const float* qcrx  = (const float*)d_in[7];
    const float* tag_w = (const float*)d_in[8];
    const float* tag_b = (const float*)d_in[9];
    float* out = (float*)d_out;

    char* ws = (char*)d_ws;
    float*  Tg   = (float*)ws;                                     // 5184 B
    float*  proj = (float*)(ws + 8192);                            // 8.192 MB
    float*  outs = (float*)(ws + 8192 + (size_t)VOCAB * 16 * 4);   // 2 MB

    setup_kernel<<<dim3(1), dim3(1024), 0, stream>>>(qrx, qry, qrz, qcrx, Tg);
    proj_kernel<<<dim3(2048), dim3(256), 0, stream>>>(emb, lin_w, lin_b, proj);
    lstm_kernel<<<dim3(128), dim3(64), 0, stream>>>(lin_w, Tg, sent, proj, outs);
    logits_kernel<<<dim3(1024), dim3(256), 0, stream>>>(outs, tag_w, tag_b, out);
}

// Round 18
// 189.669 us; speedup vs baseline: 1.0161x; 1.0161x over previous
//
#include <hip/hip_runtime.h>
#include <math.h>

#define S_LEN 256
#define BATCH 512
#define ROWS (S_LEN * BATCH)
#define VOCAB 128000

typedef float v2f __attribute__((ext_vector_type(2)));

// ---------------------------------------------------------------------------
// Compile-time reproduction of np.random.RandomState(seed) op streams.
// ---------------------------------------------------------------------------
struct MTState {
    unsigned mt[624];
    int idx;
    constexpr MTState(unsigned seed) : mt{}, idx(624) {
        mt[0] = seed;
        for (int i = 1; i < 624; ++i)
            mt[i] = 1812433253u * (mt[i - 1] ^ (mt[i - 1] >> 30)) + (unsigned)i;
    }
    constexpr unsigned next() {
        if (idx >= 624) {
            for (int i = 0; i < 624; ++i) {
                unsigned y = (mt[i] & 0x80000000u) | (mt[(i + 1) % 624] & 0x7fffffffu);
                mt[i] = mt[(i + 397) % 624] ^ (y >> 1) ^ ((y & 1u) ? 2567483615u : 0u);
            }
            idx = 0;
        }
        unsigned y = mt[idx++];
        y ^= y >> 11;
        y ^= (y << 7)  & 2636928640u;
        y ^= (y << 15) & 4022730752u;
        y ^= y >> 18;
        return y;
    }
};

struct OpsTab {
    int   k [4][20];
    int   w0[4][20];
    int   w1[4][20];
    float t [4][20];
};

constexpr OpsTab make_ops() {
    OpsTab o{};
    for (int seed = 0; seed < 4; ++seed) {
        MTState rng((unsigned)seed);
        for (int i = 0; i < 20; ++i) {
            unsigned k = rng.next() & 3u;            // randint(4)
            if (k < 3u) {
                int w = (int)(rng.next() & 3u);      // randint(4)
                unsigned A = rng.next(), B = rng.next();  // rk_double
                double d = ((double)(A >> 5) * 67108864.0 + (double)(B >> 6))
                           / 9007199254740992.0;
                o.k[seed][i]  = (int)k;
                o.w0[seed][i] = w;
                o.w1[seed][i] = 0;
                o.t[seed][i]  = (float)(6.283185307179586 * d);
            } else {
                int w0 = (int)(rng.next() & 3u);     // randint(4)
                unsigned v = rng.next() & 3u;        // randint(3): reject >2
                while (v > 2u) v = rng.next() & 3u;
                o.k[seed][i]  = 3;
                o.w0[seed][i] = w0;
                o.w1[seed][i] = (int)((w0 + 1 + (int)v) & 3);
                o.t[seed][i]  = 0.f;
            }
        }
    }
    return o;
}

__constant__ OpsTab OPS = make_ops();

// factor for product-to-sum expansion: enc_j*enc_k per wire.
__device__ inline float pfac(int t, int bj, int bk) {
    if (bj == bk)
        return (t == 0) ? 0.5f : (t == 1) ? (bj ? -0.5f : 0.5f) : 0.f;
    return (t == 2) ? 0.5f : 0.f;
}

// ---------------------------------------------------------------------------
// Setup: lane-parallel circuit fold -> M (LDS) -> Q = Re(M^T D_w M) -> T
// tensor (16 (g,w) pairs x 81 coeffs over {1,cos,sin}^4) -> global.
// ---------------------------------------------------------------------------
__global__ __launch_bounds__(1024) void setup_kernel(const float* __restrict__ qrx,
                                                     const float* __restrict__ qry,
                                                     const float* __restrict__ qrz,
                                                     const float* __restrict__ qcrx,
                                                     float* __restrict__ Tg) {
    __shared__ float Mr[4 * 256];
    __shared__ float Mi[4 * 256];
    __shared__ float Q[16 * 256];

    int tid = threadIdx.x;
    int wv  = tid >> 6;
    int l   = tid & 63;
    int g   = wv >> 2;
    int r   = l & 15;
    int col = (wv & 3) * 4 + (l >> 4);

    float ar = (r == col) ? 1.f : 0.f;
    float ai = 0.f;
    int lbase = l & 48;

    for (int o = 0; o < 20; ++o) {
        int   k  = OPS.k[g][o];
        int   w  = OPS.w0[g][o];
        float th = OPS.t[g][o];
        if (k == 3) {
            int M1  = 8 >> OPS.w1[g][o];
            int M0  = 8 >> w;
            int src = lbase | (r ^ M1);
            float br = __shfl(ar, src, 64);
            float bi = __shfl(ai, src, 64);
            bool ctrl = (r & M0) != 0;
            ar = ctrl ? br : ar;
            ai = ctrl ? bi : ai;
        } else {
            int M = 8 >> w;
            float c = cosf(0.5f * th), s = sinf(0.5f * th);
            bool hi = (r & M) != 0;
            float Ar = c, Ai = 0.f, Br = 0.f, Bi = 0.f;
            if (k == 0) { Bi = -s; }                       // RX
            else if (k == 1) { Br = hi ? s : -s; }         // RY
            else { Ai = hi ? s : -s; }                     // RZ
            int src = lbase | (r ^ M);
            float br = __shfl(ar, src, 64);
            float bi = __shfl(ai, src, 64);
            float nr = Ar * ar - Ai * ai + Br * br - Bi * bi;
            float ni = Ar * ai + Ai * ar + Br * bi + Bi * br;
            ar = nr; ai = ni;
        }
    }

    for (int w = 0; w < 4; ++w) {
        int M  = 8 >> w;
        int M1 = 8 >> ((w + 1) & 3);
        bool hi = (r & M) != 0;
        int src = lbase | (r ^ M);
        float th, c, s, br, bi, nr, ni;

        th = qrx[g * 4 + w]; c = cosf(0.5f * th); s = sinf(0.5f * th);
        br = __shfl(ar, src, 64); bi = __shfl(ai, src, 64);
        nr = c * ar + s * bi;  ni = c * ai - s * br;       // RX
        ar = nr; ai = ni;

        th = qry[g * 4 + w]; c = cosf(0.5f * th); s = sinf(0.5f * th);
        br = __shfl(ar, src, 64); bi = __shfl(ai, src, 64);
        { float B = hi ? s : -s;
          nr = c * ar + B * br;  ni = c * ai + B * bi; }   // RY
        ar = nr; ai = ni;

        th = qrz[g * 4 + w]; c = cosf(0.5f * th); s = sinf(0.5f * th);
        { float Ai2 = hi ? s : -s;
          nr = c * ar - Ai2 * ai;  ni = c * ai + Ai2 * ar; } // RZ
        ar = nr; ai = ni;

        th = qcrx[g * 4 + w]; c = cosf(0.5f * th); s = sinf(0.5f * th);
        int src1 = lbase | (r ^ M1);
        br = __shfl(ar, src1, 64); bi = __shfl(ai, src1, 64);
        bool ctrl = hi;
        nr = c * ar + s * bi;  ni = c * ai - s * br;       // CRX
        ar = ctrl ? nr : ar;
        ai = ctrl ? ni : ai;
    }

    Mr[g * 256 + r * 16 + col] = ar;
    Mi[g * 256 + r * 16 + col] = ai;
    __syncthreads();

    for (int n = 0; n < 4; ++n) {
        int i  = tid * 4 + n;
        int gw = i >> 8, j = (i >> 4) & 15, kk = i & 15;
        int gg2 = gw >> 2, w = gw & 3;
        float acc = 0.f;
        for (int rr = 0; rr < 16; ++rr) {
            float sgn = ((rr >> (3 - w)) & 1) ? -1.f : 1.f;
            float mrj = Mr[gg2 * 256 + rr * 16 + j], mrk = Mr[gg2 * 256 + rr * 16 + kk];
            float mij = Mi[gg2 * 256 + rr * 16 + j], mik = Mi[gg2 * 256 + rr * 16 + kk];
            acc += sgn * (mrj * mrk + mij * mik);
        }
        Q[gw * 256 + j * 16 + kk] = acc;
    }
    __syncthreads();

    if (tid < 144) {
        int gw = tid / 9, rem = tid % 9, t0 = rem / 3, t1 = rem % 3;
        float acc[3][3] = {};
        for (int jk = 0; jk < 256; ++jk) {
            int j = jk >> 4, kq = jk & 15;
            int bj0 = (j >> 3) & 1, bk0 = (kq >> 3) & 1;
            int bj1 = (j >> 2) & 1, bk1 = (kq >> 2) & 1;
            int bj2 = (j >> 1) & 1, bk2 = (kq >> 1) & 1;
            int bj3 = j & 1,        bk3 = kq & 1;
            float f01 = pfac(t0, bj0, bk0) * pfac(t1, bj1, bk1);
            float base = Q[gw * 256 + jk] * f01;
#pragma unroll
            for (int t2 = 0; t2 < 3; ++t2) {
                float f2 = pfac(t2, bj2, bk2);
#pragma unroll
                for (int t3 = 0; t3 < 3; ++t3) {
                    float f3 = pfac(t3, bj3, bk3);
                    acc[t2][t3] = fmaf(base, f2 * f3, acc[t2][t3]);
                }
            }
        }
#pragma unroll
        for (int t2 = 0; t2 < 3; ++t2)
#pragma unroll
            for (int t3 = 0; t3 < 3; ++t3)
                Tg[gw * 81 + t0 * 27 + t1 * 9 + t2 * 3 + t3] = acc[t2][t3];
    }
}

// ---------------------------------------------------------------------------
// proj kernel v5 (R15/R17 measured): dense global loads + DPP row_shr
// reduction, zero LDS.  Lane ch==15 of each 16-group stores a float4.
// ---------------------------------------------------------------------------
template <int CTRL>
__device__ inline float dpp_shr_add(float p) {
    int t = __builtin_amdgcn_update_dpp(0, __float_as_int(p), CTRL, 0xf, 0xf, true);
    return p + __int_as_float(t);
}

__global__ __launch_bounds__(256) void proj_kernel(const float* __restrict__ emb,
                                                   const float* __restrict__ lin_w,
                                                   const float* __restrict__ lin_b,
                                                   float* __restrict__ proj) {
    int tid = threadIdx.x;
    int l   = tid & 63;
    int wv  = tid >> 6;          // q-group
    int ch  = l & 15;            // d-chunk lane
    int rl  = l >> 4;            // row within group of 4

    float wq[4][16];
#pragma unroll
    for (int qq = 0; qq < 4; ++qq) {
        const float* wr = lin_w + (wv * 4 + qq) * 260 + ch * 4;
#pragma unroll
        for (int j = 0; j < 4; ++j) {
            float4 t = *(const float4*)(wr + j * 64);
            wq[qq][j * 4 + 0] = t.x; wq[qq][j * 4 + 1] = t.y;
            wq[qq][j * 4 + 2] = t.z; wq[qq][j * 4 + 3] = t.w;
        }
    }
    float4 bz = *(const float4*)(lin_b + wv * 4);

    const int ntiles = VOCAB / 16;   // 8000
    for (int tile = blockIdx.x; tile < ntiles; tile += gridDim.x) {
        const float* base = emb + (size_t)tile * 16 * 256;
#pragma unroll
        for (int r4 = 0; r4 < 4; ++r4) {
            int row = r4 * 4 + rl;
            const float* rp = base + row * 256 + ch * 4;
            float xs[16];
            *(float4*)&xs[0]  = *(const float4*)(rp + 0 * 64);
            *(float4*)&xs[4]  = *(const float4*)(rp + 1 * 64);
            *(float4*)&xs[8]  = *(const float4*)(rp + 2 * 64);
            *(float4*)&xs[12] = *(const float4*)(rp + 3 * 64);

            float p0 = 0.f, p1 = 0.f, p2 = 0.f, p3 = 0.f;
#pragma unroll
            for (int d = 0; d < 16; ++d) {
                p0 = fmaf(xs[d], wq[0][d], p0);
                p1 = fmaf(xs[d], wq[1][d], p1);
                p2 = fmaf(xs[d], wq[2][d], p2);
                p3 = fmaf(xs[d], wq[3][d], p3);
            }

            p0 = dpp_shr_add<0x111>(p0); p1 = dpp_shr_add<0x111>(p1);
            p2 = dpp_shr_add<0x111>(p2); p3 = dpp_shr_add<0x111>(p3);
            p0 = dpp_shr_add<0x112>(p0); p1 = dpp_shr_add<0x112>(p1);
            p2 = dpp_shr_add<0x112>(p2); p3 = dpp_shr_add<0x112>(p3);
            p0 = dpp_shr_add<0x114>(p0); p1 = dpp_shr_add<0x114>(p1);
            p2 = dpp_shr_add<0x114>(p2); p3 = dpp_shr_add<0x114>(p3);
            p0 = dpp_shr_add<0x118>(p0); p1 = dpp_shr_add<0x118>(p1);
            p2 = dpp_shr_add<0x118>(p2); p3 = dpp_shr_add<0x118>(p3);

            if (ch == 15) {
                float4 o = make_float4(p0 + bz.x, p1 + bz.y, p2 + bz.z, p3 + bz.w);
                *(float4*)(proj + ((size_t)(tile * 16 + row) * 16 + wv * 4)) = o;
            }
        }
    }
}

// ---------------------------------------------------------------------------
// Recurrence (R16 instruction-diet, measured 81.4 us): packed-f32 polynomial
// + raw v_sin/v_cos; lane l = (q<<4)|(w<<2)|g; DPP broadcasts; depth-4
// prefetch.
// ---------------------------------------------------------------------------
__device__ inline float fast_sig(float k, float x) {
    return __builtin_amdgcn_rcpf(1.f + __expf(-k * x));
}

#define INV2PI 0.15915494309189535f

__global__ __launch_bounds__(64)
__attribute__((amdgpu_waves_per_eu(1, 1)))
void lstm_kernel(const float* __restrict__ lin_w,
                 const float* __restrict__ Tg,
                 const int* __restrict__ sent,
                 const float* __restrict__ proj,
                 float* __restrict__ outs) {
    int l = threadIdx.x;
    int g = l & 3;
    int w = (l >> 2) & 3;
    int q = l >> 4;
    int b = blockIdx.x * 4 + q;

    v2f   TV[27];
    float TS[27];
#pragma unroll
    for (int c = 0; c < 27; ++c) {
        const float* tp = Tg + (g * 4 + w) * 81 + c * 3;
        TV[c] = (v2f){tp[0], tp[1]};
        TS[c] = tp[2];
    }

    float whp[4][4];
#pragma unroll
    for (int qq = 0; qq < 4; ++qq)
#pragma unroll
        for (int k = 0; k < 4; ++k)
            whp[qq][k] = lin_w[(g * 4 + qq) * 260 + 256 + ((w - k) & 3)];

    const float kk = (g == 2) ? 2.f : 1.f;
    const float sc = (g == 2) ? 2.f : 1.f;
    const float of = (g == 2) ? 1.f : 0.f;

    float hr0 = 0.f, hr1 = 0.f, hr2 = 0.f, hr3 = 0.f, cst = 0.f;

    const int* sp = sent + b;
    float* op = outs + (size_t)b * 4 + w;

    auto tokat = [&](int sidx) { return sp[(size_t)(sidx & 255) * BATCH]; };
    auto rowat = [&](int tok)  { return *(const float4*)(proj + (size_t)tok * 16 + g * 4); };

    int tk0 = tokat(4), tk1 = tokat(5), tk2 = tokat(6), tk3 = tokat(7);
    float4 A0 = rowat(tokat(0));
    float4 A1 = rowat(tokat(1));
    float4 A2 = rowat(tokat(2));
    float4 A3 = rowat(tokat(3));

    auto step = [&](float4 ax, int sidx) {
        float a0 = fmaf(whp[0][3], hr3, fmaf(whp[0][2], hr2, fmaf(whp[0][1], hr1, fmaf(whp[0][0], hr0, ax.x))));
        float a1 = fmaf(whp[1][3], hr3, fmaf(whp[1][2], hr2, fmaf(whp[1][1], hr1, fmaf(whp[1][0], hr0, ax.y))));
        float a2 = fmaf(whp[2][3], hr3, fmaf(whp[2][2], hr2, fmaf(whp[2][1], hr1, fmaf(whp[2][0], hr0, ax.z))));
        float a3 = fmaf(whp[3][3], hr3, fmaf(whp[3][2], hr2, fmaf(whp[3][1], hr1, fmaf(whp[3][0], hr0, ax.w))));

        float r0 = a0 * INV2PI, r1 = a1 * INV2PI, r2 = a2 * INV2PI, r3 = a3 * INV2PI;
        float s0 = __builtin_amdgcn_sinf(r0), c0 = __builtin_amdgcn_cosf(r0);
        float s1 = __builtin_amdgcn_sinf(r1), c1 = __builtin_amdgcn_cosf(r1);
        float s2 = __builtin_amdgcn_sinf(r2), c2 = __builtin_amdgcn_cosf(r2);
        float s3 = __builtin_amdgcn_sinf(r3), c3 = __builtin_amdgcn_cosf(r3);

        v2f c2v = {c2, c2}, s2v = {s2, s2};
        v2f c1v = {c1, c1}, s1v = {s1, s1};
        v2f c0v = {c0, c0}, s0v = {s0, s0};

        v2f   yAv[9];
        float yAs[9];
#pragma unroll
        for (int c = 0; c < 9; ++c) {
            yAv[c] = __builtin_elementwise_fma(s2v, TV[c * 3 + 2],
                       __builtin_elementwise_fma(c2v, TV[c * 3 + 1], TV[c * 3 + 0]));
            yAs[c] = fmaf(s2, TS[c * 3 + 2], fmaf(c2, TS[c * 3 + 1], TS[c * 3 + 0]));
        }
        v2f   yBv[3];
        float yBs[3];
#pragma unroll
        for (int c = 0; c < 3; ++c) {
            yBv[c] = __builtin_elementwise_fma(s1v, yAv[c * 3 + 2],
                       __builtin_elementwise_fma(c1v, yAv[c * 3 + 1], yAv[c * 3 + 0]));
            yBs[c] = fmaf(s1, yAs[c * 3 + 2], fmaf(c1, yAs[c * 3 + 1], yAs[c * 3 + 0]));
        }
        v2f   yCv = __builtin_elementwise_fma(s0v, yBv[2],
                      __builtin_elementwise_fma(c0v, yBv[1], yBv[0]));
        float yCs = fmaf(s0, yBs[2], fmaf(c0, yBs[1], yBs[0]));
        float Z = fmaf(s3, yCs, fmaf(c3, yCv.y, yCv.x));

        float act = fmaf(sc, fast_sig(kk, Z), -of);

        int ai2 = __float_as_int(act);
        float f  = __int_as_float(__builtin_amdgcn_update_dpp(0, ai2, 0x00, 0xf, 0xf, true));
        float ii = __int_as_float(__builtin_amdgcn_update_dpp(0, ai2, 0x55, 0xf, 0xf, true));
        float gg = __int_as_float(__builtin_amdgcn_update_dpp(0, ai2, 0xAA, 0xf, 0xf, true));
        float oo = __int_as_float(__builtin_amdgcn_update_dpp(0, ai2, 0xFF, 0xf, 0xf, true));

        cst = fmaf(f, cst, ii * gg);
        float tn = fmaf(2.f, fast_sig(2.f, cst), -1.f);
        float hme = oo * tn;

        if (g == 0) op[(size_t)sidx * 2048] = hme;

        int hi = __float_as_int(hme);
        hr0 = hme;
        hr1 = __int_as_float(__builtin_amdgcn_update_dpp(hi, hi, 0x124, 0xf, 0xf, false));
        hr2 = __int_as_float(__builtin_amdgcn_update_dpp(hi, hi, 0x128, 0xf, 0xf, false));
        hr3 = __int_as_float(__builtin_amdgcn_update_dpp(hi, hi, 0x12C, 0xf, 0xf, false));
    };

    for (int s = 0; s < S_LEN; s += 4) {
        step(A0, s);     A0 = rowat(tk0); tk0 = tokat(s + 8);
        step(A1, s + 1); A1 = rowat(tk1); tk1 = tokat(s + 9);
        step(A2, s + 2); A2 = rowat(tk2); tk2 = tokat(s + 10);
        step(A3, s + 3); A3 = rowat(tk3); tk3 = tokat(s + 11);
    }
}

// ---------------------------------------------------------------------------
// logits + log_softmax v2 (R12 measured ~-30us vs v1): 4 lanes per row,
// lane owns 16 tags (weights in 64 regs), 2-stage quad shuffles, contiguous
// float4 stores.  Grid exact: 2048 x 4 waves x 16 rows = 131072 rows.
// ---------------------------------------------------------------------------
__global__ __launch_bounds__(256) void logits_kernel(const float* __restrict__ outs,
                                                     const float* __restrict__ tag_w,
                                                     const float* __restrict__ tag_b,
                                                     float* __restrict__ out) {
    int tid = blockIdx.x * 256 + threadIdx.x;
    int wid = tid >> 6;
    int l   = threadIdx.x & 63;
    int row = wid * 16 + (l >> 2);
    int t0  = (l & 3) * 16;

    float tw[16][4], tb[16];
#pragma unroll
    for (int t = 0; t < 16; ++t) {
        float4 v = *(const float4*)(tag_w + (t0 + t) * 4);
        tw[t][0] = v.x; tw[t][1] = v.y; tw[t][2] = v.z; tw[t][3] = v.w;
        tb[t] = tag_b[t0 + t];
    }

    float4 h = *(const float4*)(outs + (size_t)row * 4);

    float z[16];
#pragma unroll
    for (int t = 0; t < 16; ++t)
        z[t] = fmaf(h.w, tw[t][3], fmaf(h.z, tw[t][2],
                fmaf(h.y, tw[t][1], fmaf(h.x, tw[t][0], tb[t]))));

    float m = z[0];
#pragma unroll
    for (int t = 1; t < 16; ++t) m = fmaxf(m, z[t]);
    m = fmaxf(m, __shfl_xor(m, 1, 64));
    m = fmaxf(m, __shfl_xor(m, 2, 64));

    float e = 0.f;
#pragma unroll
    for (int t = 0; t < 16; ++t) e += __expf(z[t] - m);
    e += __shfl_xor(e, 1, 64);
    e += __shfl_xor(e, 2, 64);

    float lg = m + __logf(e);
    float* op = out + (size_t)row * 64 + t0;
#pragma unroll
    for (int t = 0; t < 16; t += 4) {
        float4 o = make_float4(z[t] - lg, z[t + 1] - lg, z[t + 2] - lg, z[t + 3] - lg);
        *(float4*)(op + t) = o;
    }
}

// ---------------------------------------------------------------------------
extern "C" void kernel_launch(void* const* d_in, const int* in_sizes, int n_in,
                              void* d_out, int out_size, void* d_ws, size_t ws_size,
                              hipStream_t stream) {
    const int*   sent  = (const int*)d_in[0];
    const float* emb   = (const float*)d_in[1];
    const float* lin_w = (const float*)d_in[2];
    const float* lin_b = (const float*)d_in[3];
    const float* qrx   = (const float*)d_in[4];
    const float* qry   = (const float*)d_in[5];
    const float* qrz   = (const float*)d_in[6];
    const float* qcrx  = (const float*)d_in[7];
    const float* tag_w = (const float*)d_in[8];
    const float* tag_b = (const float*)d_in[9];
    float* out = (float*)d_out;

    char* ws = (char*)d_ws;
    float*  Tg   = (float*)ws;                                     // 5184 B
    float*  proj = (float*)(ws + 8192);                            // 8.192 MB
    float*  outs = (float*)(ws + 8192 + (size_t)VOCAB * 16 * 4);   // 2 MB

    setup_kernel<<<dim3(1), dim3(1024), 0, stream>>>(qrx, qry, qrz, qcrx, Tg);
    proj_kernel<<<dim3(2048), dim3(256), 0, stream>>>(emb, lin_w, lin_b, proj);
    lstm_kernel<<<dim3(128), dim3(64), 0, stream>>>(lin_w, Tg, sent, proj, outs);
    logits_kernel<<<dim3(2048), dim3(256), 0, stream>>>(outs, tag_w, tag_b, out);
}